// Round 1
// baseline (4931.763 us; speedup 1.0000x reference)
//
#include <hip/hip_runtime.h>
#include <math.h>

typedef unsigned short u16;
using bf16x8 = __attribute__((ext_vector_type(8))) short;
using f32x4  = __attribute__((ext_vector_type(4))) float;

#define DEV __device__ __forceinline__

constexpr int Bc = 32, Cc = 3, IMGc = 224, Pc = 16, Dc = 768, Lc = 12, Hc = 12, NCLSc = 1000;
constexpr int NPc = 196, Nc = 197, DHc = 64;
constexpr int M0 = Bc * Nc;        // 6304 valid token rows
constexpr int MP = 6400;           // padded to 50*128
constexpr int MPATCH = Bc * NPc;   // 6272 = 49*128
constexpr int NKP = 224;           // padded key count (7*32)
constexpr int NB = Bc * Hc;        // 384 attention batches

DEV u16 f2b(float f) { union { float f; unsigned u; } c; c.f = f; unsigned r = c.u + 0x7fffu + ((c.u >> 16) & 1u); return (u16)(r >> 16); }
DEV float b2f(u16 b) { union { float f; unsigned u; } c; c.u = ((unsigned)b) << 16; return c.f; }

DEV float wsum(float v) {
#pragma unroll
  for (int m = 32; m >= 1; m >>= 1) v += __shfl_xor(v, m, 64);
  return v;
}
DEV float wmax(float v) {
#pragma unroll
  for (int m = 32; m >= 1; m >>= 1) v = fmaxf(v, __shfl_xor(v, m, 64));
  return v;
}

DEV void load_lds16(const u16* g, u16* l) {
  __builtin_amdgcn_global_load_lds((const __attribute__((address_space(1))) void*)g,
                                   (__attribute__((address_space(3))) void*)l, 16, 0, 0);
}

// ---------------- elementwise kernels ----------------

__global__ void cvt_kern(const float* __restrict__ in, u16* __restrict__ out, long n4) {
  long i = (long)blockIdx.x * 256 + threadIdx.x;
  if (i >= n4) return;
  float4 v = ((const float4*)in)[i];
  ushort4 r;
  r.x = f2b(v.x); r.y = f2b(v.y); r.z = f2b(v.z); r.w = f2b(v.w);
  ((ushort4*)out)[i] = r;
}

__global__ void patchify_kern(const float* __restrict__ img, u16* __restrict__ Xp) {
  int i = blockIdx.x * 256 + threadIdx.x;
  if (i >= MPATCH * Dc) return;
  int r = i / Dc, f = i - r * Dc;
  int b = r / NPc, g = r - b * NPc;
  int gi = g / 14, gj = g - gi * 14;
  int c = f % 3, t2 = f / 3;
  int pj = t2 & 15, pi = t2 >> 4;
  float v = img[(((long)(b * 3 + c) * 224) + gi * 16 + pi) * 224 + gj * 16 + pj];
  Xp[i] = f2b(v);
}

__global__ void addpos_kern(float* __restrict__ x, const float* __restrict__ cls, const float* __restrict__ pos) {
  int i = blockIdx.x * 256 + threadIdx.x;  // over M0*192 float4
  if (i >= M0 * 192) return;
  int row = i / 192, q = i - row * 192;
  int n = row % Nc;
  float4 p = ((const float4*)pos)[n * 192 + q];
  float4* dst = (float4*)x + (long)row * 192 + q;
  if (n == 0) {
    float4 cv = ((const float4*)cls)[q];
    float4 o; o.x = cv.x + p.x; o.y = cv.y + p.y; o.z = cv.z + p.z; o.w = cv.w + p.w;
    *dst = o;
  } else {
    float4 o = *dst;
    o.x += p.x; o.y += p.y; o.z += p.z; o.w += p.w;
    *dst = o;
  }
}

__global__ __launch_bounds__(256) void ln_kern(const float* __restrict__ x, const float* __restrict__ w,
                                               const float* __restrict__ b, u16* __restrict__ out, int rows) {
  int wid = threadIdx.x >> 6, l = threadIdx.x & 63;
  int row = blockIdx.x * 4 + wid;
  if (row >= rows) return;
  const float4* xr = (const float4*)(x + (long)row * Dc);
  float4 v[3];
#pragma unroll
  for (int i = 0; i < 3; ++i) v[i] = xr[i * 64 + l];
  float s = 0;
#pragma unroll
  for (int i = 0; i < 3; ++i) s += v[i].x + v[i].y + v[i].z + v[i].w;
  s = wsum(s);
  float mean = s * (1.0f / Dc);
  float ss = 0;
#pragma unroll
  for (int i = 0; i < 3; ++i) {
    float a0 = v[i].x - mean, a1 = v[i].y - mean, a2 = v[i].z - mean, a3 = v[i].w - mean;
    ss += a0 * a0 + a1 * a1 + a2 * a2 + a3 * a3;
  }
  ss = wsum(ss);
  float rs = rsqrtf(ss * (1.0f / Dc) + 1e-5f);
  const float4* w4 = (const float4*)w;
  const float4* b4 = (const float4*)b;
#pragma unroll
  for (int i = 0; i < 3; ++i) {
    int pos = i * 64 + l;
    float4 wv = w4[pos], bv = b4[pos];
    ushort4 o;
    o.x = f2b((v[i].x - mean) * rs * wv.x + bv.x);
    o.y = f2b((v[i].y - mean) * rs * wv.y + bv.y);
    o.z = f2b((v[i].z - mean) * rs * wv.z + bv.z);
    o.w = f2b((v[i].w - mean) * rs * wv.w + bv.w);
    ((ushort4*)out)[(long)row * 192 + pos] = o;
  }
}

// softmax in-place on bf16 scores S[z][224][224], valid rows/cols = 197
__global__ __launch_bounds__(256) void softmax_kern(u16* __restrict__ S) {
  int wid = threadIdx.x >> 6, l = threadIdx.x & 63;
  int q = blockIdx.x * 4 + wid;
  if (q >= Nc) return;
  int z = blockIdx.y;
  u16* rowp = S + ((long)z * NKP + q) * NKP;
  float vals[4];
  float mx = -1e30f;
#pragma unroll
  for (int i = 0; i < 4; ++i) {
    int col = i * 64 + l;
    float vv = (col < Nc) ? b2f(rowp[col]) : -1e30f;
    vals[i] = vv;
    mx = fmaxf(mx, vv);
  }
  mx = wmax(mx);
  float sum = 0;
#pragma unroll
  for (int i = 0; i < 4; ++i) {
    int col = i * 64 + l;
    float e = (col < Nc) ? expf(vals[i] - mx) : 0.f;
    vals[i] = e;
    sum += e;
  }
  sum = wsum(sum);
  float inv = 1.0f / sum;
#pragma unroll
  for (int i = 0; i < 4; ++i) {
    int col = i * 64 + l;
    if (col < NKP) rowp[col] = (col < Nc) ? f2b(vals[i] * inv) : (u16)0;
  }
}

__global__ void latent_kern(const float* __restrict__ x, u16* __restrict__ lat) {
  int i = blockIdx.x * 256 + threadIdx.x;
  if (i >= Bc * Dc) return;
  int b = i / Dc, d = i - b * Dc;
  lat[i] = f2b(x[(long)(b * Nc) * Dc + d]);
}

// ---------------- generic MFMA GEMM: C = A @ W^T (+epilogue) ----------------

enum { EPI_F32 = 0, EPI_PATCH, EPI_BF16, EPI_PV, EPI_RES, EPI_GELU, EPI_TANH, EPI_QKV };

struct GP {
  const u16* A; const u16* W;
  int lda, ldb, ldc;
  long sA, sW, sC;          // per-batch strides (elements)
  int K;
  int Aclamp, Wclamp;       // valid source rows (staging clamp)
  int Mv, Nv;               // write guards
  float alpha;
  const float* bias;
  float* Cf; u16* Cb;
  u16 *q, *k, *v;
};

template <int EPI>
__global__ __launch_bounds__(256) void gemm_bt(GP p) {
  __shared__ alignas(16) u16 As[128 * 32];
  __shared__ alignas(16) u16 Ws[128 * 32];
  const int z = blockIdx.z;
  const u16* Ab = p.A + (long)z * p.sA;
  const u16* Wb = p.W + (long)z * p.sW;
  const int tid = threadIdx.x;
  const int l = tid & 63, wid = tid >> 6;
  const int quad = l >> 4, lr = l & 15;
  const int wr = wid >> 1, wc = wid & 1;
  const int tm = blockIdx.y * 128, tn = blockIdx.x * 128;

  f32x4 acc[4][4];
  f32x4 z4 = {0.f, 0.f, 0.f, 0.f};
#pragma unroll
  for (int i = 0; i < 4; ++i)
#pragma unroll
    for (int j = 0; j < 4; ++j) acc[i][j] = z4;

  const int sr = tid >> 2;
  const int sc = (tid & 3) * 8;
  const int ar0 = min(tm + sr, p.Aclamp - 1);
  const int ar1 = min(tm + 64 + sr, p.Aclamp - 1);
  const int wrr0 = min(tn + sr, p.Wclamp - 1);
  const int wrr1 = min(tn + 64 + sr, p.Wclamp - 1);
  const u16* a0 = Ab + (long)ar0 * p.lda + sc;
  const u16* a1 = Ab + (long)ar1 * p.lda + sc;
  const u16* w0 = Wb + (long)wrr0 * p.ldb + sc;
  const u16* w1 = Wb + (long)wrr1 * p.ldb + sc;

  for (int k0 = 0; k0 < p.K; k0 += 32) {
    load_lds16(a0 + k0, &As[tid * 8]);
    load_lds16(a1 + k0, &As[2048 + tid * 8]);
    load_lds16(w0 + k0, &Ws[tid * 8]);
    load_lds16(w1 + k0, &Ws[2048 + tid * 8]);
    __syncthreads();
    bf16x8 af[4], wf[4];
#pragma unroll
    for (int mi = 0; mi < 4; ++mi) af[mi] = *(const bf16x8*)&As[(wr * 64 + mi * 16 + lr) * 32 + quad * 8];
#pragma unroll
    for (int ni = 0; ni < 4; ++ni) wf[ni] = *(const bf16x8*)&Ws[(wc * 64 + ni * 16 + lr) * 32 + quad * 8];
#pragma unroll
    for (int mi = 0; mi < 4; ++mi)
#pragma unroll
      for (int ni = 0; ni < 4; ++ni)
        acc[mi][ni] = __builtin_amdgcn_mfma_f32_16x16x32_bf16(af[mi], wf[ni], acc[mi][ni], 0, 0, 0);
    __syncthreads();
  }

  if constexpr (EPI == EPI_QKV) {
    int hh[4], dh[4], ss[4]; float bv[4];
#pragma unroll
    for (int ni = 0; ni < 4; ++ni) {
      int col = tn + wc * 64 + ni * 16 + lr;
      hh[ni] = col / 192;
      int rem = col - hh[ni] * 192;
      dh[ni] = rem / 3;
      ss[ni] = rem - 3 * dh[ni];
      bv[ni] = p.bias[col];
    }
#pragma unroll
    for (int mi = 0; mi < 4; ++mi)
#pragma unroll
      for (int j = 0; j < 4; ++j) {
        int row = tm + wr * 64 + mi * 16 + quad * 4 + j;
        if (row >= p.Mv) continue;
        int b = row / Nc, n = row - Nc * b;
#pragma unroll
        for (int ni = 0; ni < 4; ++ni) {
          float val = acc[mi][ni][j] + bv[ni];
          if (ss[ni] == 0) {
            val *= p.alpha;
            p.q[(((long)(b * Hc + hh[ni])) * Nc + n) * DHc + dh[ni]] = f2b(val);
          } else if (ss[ni] == 1) {
            p.k[(((long)(b * Hc + hh[ni])) * Nc + n) * DHc + dh[ni]] = f2b(val);
          } else {
            p.v[(((long)(b * Hc + hh[ni])) * DHc + dh[ni]) * NKP + n] = f2b(val);
          }
        }
      }
  } else {
#pragma unroll
    for (int mi = 0; mi < 4; ++mi)
#pragma unroll
      for (int j = 0; j < 4; ++j) {
        int row = tm + wr * 64 + mi * 16 + quad * 4 + j;
        if (row >= p.Mv) continue;
#pragma unroll
        for (int ni = 0; ni < 4; ++ni) {
          int col = tn + wc * 64 + ni * 16 + lr;
          if (col >= p.Nv) continue;
          float val = acc[mi][ni][j];
          if constexpr (EPI == EPI_F32) {
            p.Cf[(long)z * p.sC + (long)row * p.ldc + col] = val + p.bias[col];
          }
          if constexpr (EPI == EPI_PATCH) {
            int b = row / NPc, t = row - NPc * b;
            p.Cf[((long)(b * Nc + 1 + t)) * p.ldc + col] = val + p.bias[col];
          }
          if constexpr (EPI == EPI_BF16) {
            p.Cb[(long)z * p.sC + (long)row * p.ldc + col] = f2b(val);
          }
          if constexpr (EPI == EPI_PV) {
            long off = (long)(z / Hc) * (Nc * Dc) + (long)(z % Hc) * DHc;
            p.Cb[off + (long)row * Dc + col] = f2b(val);
          }
          if constexpr (EPI == EPI_RES) {
            long ix = (long)row * p.ldc + col;
            p.Cf[ix] += val + p.bias[col];
          }
          if constexpr (EPI == EPI_GELU) {
            float t2 = val + p.bias[col];
            p.Cb[(long)row * p.ldc + col] = f2b(0.5f * t2 * (1.0f + erff(t2 * 0.70710678118f)));
          }
          if constexpr (EPI == EPI_TANH) {
            float t2 = val + p.bias[col];
            p.Cb[(long)row * p.ldc + col] = f2b(tanhf(t2));
          }
        }
      }
  }
}

// ---------------- host ----------------

static void cvt(const float* in, u16* out, long n, hipStream_t s) {
  long n4 = n / 4;
  cvt_kern<<<dim3((unsigned)((n4 + 255) / 256)), dim3(256), 0, s>>>(in, out, n4);
}

extern "C" void kernel_launch(void* const* d_in, const int* in_sizes, int n_in,
                              void* d_out, int out_size, void* d_ws, size_t ws_size,
                              hipStream_t stream) {
  const float* img     = (const float*)d_in[0];
  const float* patch_w = (const float*)d_in[1];
  const float* patch_b = (const float*)d_in[2];
  const float* cls_tok = (const float*)d_in[3];
  const float* pos_emb = (const float*)d_in[4];
  const float* ln1_w   = (const float*)d_in[5];
  const float* ln1_b   = (const float*)d_in[6];
  const float* qkv_w   = (const float*)d_in[7];
  const float* qkv_b   = (const float*)d_in[8];
  const float* proj_w  = (const float*)d_in[9];
  const float* proj_b  = (const float*)d_in[10];
  const float* ln2_w   = (const float*)d_in[11];
  const float* ln2_b   = (const float*)d_in[12];
  const float* ff1_w   = (const float*)d_in[13];
  const float* ff1_b   = (const float*)d_in[14];
  const float* ff2_w   = (const float*)d_in[15];
  const float* ff2_b   = (const float*)d_in[16];
  const float* h1_w    = (const float*)d_in[17];
  const float* h1_b    = (const float*)d_in[18];
  const float* h2_w    = (const float*)d_in[19];
  const float* h2_b    = (const float*)d_in[20];
  float* out = (float*)d_out;

  char* ws = (char*)d_ws;
  auto alloc = [&](long bytes) { char* p = ws; ws += (bytes + 255) & ~255L; return p; };
  u16* Wq  = (u16*)alloc(2304L * 768 * 2);
  u16* Wp  = (u16*)alloc(768L * 768 * 2);
  u16* Wf1 = (u16*)alloc(3072L * 768 * 2);
  u16* Wf2 = (u16*)alloc(768L * 3072 * 2);
  u16* Wpa = (u16*)alloc(768L * 768 * 2);
  u16* Wh1 = (u16*)alloc(3072L * 768 * 2);
  u16* Wh2 = (u16*)alloc(1000L * 3072 * 2);
  u16* Xp  = (u16*)alloc((long)MPATCH * Dc * 2);
  float* x = (float*)alloc((long)MP * Dc * 4);
  u16* hb  = (u16*)alloc((long)MP * Dc * 2);
  u16* qb  = (u16*)alloc((long)NB * Nc * DHc * 2);
  u16* kb  = (u16*)alloc((long)NB * Nc * DHc * 2);
  u16* vt  = (u16*)alloc((long)NB * DHc * NKP * 2);
  u16* S   = (u16*)alloc((long)NB * NKP * NKP * 2);
  u16* ao  = (u16*)alloc((long)MP * Dc * 2);
  u16* gb  = (u16*)alloc((long)MP * 3072 * 2);
  u16* lat = (u16*)alloc(Bc * 768L * 2);
  u16* tb  = (u16*)alloc(Bc * 3072L * 2);
  if ((size_t)(ws - (char*)d_ws) > ws_size) return;  // workspace too small

  // one-time weight converts
  cvt(patch_w, Wpa, 768L * 768, stream);
  cvt(h1_w, Wh1, 3072L * 768, stream);
  cvt(h2_w, Wh2, 1000L * 3072, stream);

  // patchify + patch GEMM + pos/cls
  patchify_kern<<<dim3((MPATCH * Dc + 255) / 256), dim3(256), 0, stream>>>(img, Xp);
  {
    GP p{};
    p.A = Xp; p.W = Wpa; p.lda = 768; p.ldb = 768; p.ldc = 768;
    p.K = 768; p.Aclamp = MPATCH; p.Wclamp = 768; p.Mv = MPATCH; p.Nv = 768;
    p.bias = patch_b; p.Cf = x;
    gemm_bt<EPI_PATCH><<<dim3(6, 49, 1), 256, 0, stream>>>(p);
  }
  addpos_kern<<<dim3((M0 * 192 + 255) / 256), dim3(256), 0, stream>>>(x, cls_tok, pos_emb);

  for (int layer = 0; layer < Lc; ++layer) {
    cvt(qkv_w + (long)layer * 2304 * 768, Wq, 2304L * 768, stream);
    cvt(proj_w + (long)layer * 768 * 768, Wp, 768L * 768, stream);
    cvt(ff1_w + (long)layer * 3072 * 768, Wf1, 3072L * 768, stream);
    cvt(ff2_w + (long)layer * 768 * 3072, Wf2, 768L * 3072, stream);

    ln_kern<<<dim3(MP / 4), 256, 0, stream>>>(x, ln1_w + layer * 768, ln1_b + layer * 768, hb, MP);

    {  // QKV + scatter (scale folded into q)
      GP p{};
      p.A = hb; p.W = Wq; p.lda = 768; p.ldb = 768;
      p.K = 768; p.Aclamp = MP; p.Wclamp = 2304; p.Mv = M0; p.Nv = 2304;
      p.alpha = 0.125f; p.bias = qkv_b + layer * 2304;
      p.q = qb; p.k = kb; p.v = vt;
      gemm_bt<EPI_QKV><<<dim3(18, 50, 1), 256, 0, stream>>>(p);
    }
    {  // scores: S[z] = Q[z] @ K[z]^T  (bf16 out)
      GP p{};
      p.A = qb; p.W = kb; p.lda = DHc; p.ldb = DHc; p.ldc = NKP;
      p.sA = (long)Nc * DHc; p.sW = (long)Nc * DHc; p.sC = (long)NKP * NKP;
      p.K = DHc; p.Aclamp = Nc; p.Wclamp = Nc; p.Mv = Nc; p.Nv = NKP;
      p.Cb = S;
      gemm_bt<EPI_BF16><<<dim3(2, 2, NB), 256, 0, stream>>>(p);
    }
    softmax_kern<<<dim3(50, NB), 256, 0, stream>>>(S);
    {  // PV: attnout[b, q, h*64+dh] = P[z] @ V[z]
      GP p{};
      p.A = S; p.W = vt; p.lda = NKP; p.ldb = NKP;
      p.sA = (long)NKP * NKP; p.sW = (long)DHc * NKP;
      p.K = NKP; p.Aclamp = Nc; p.Wclamp = DHc; p.Mv = Nc; p.Nv = DHc;
      p.Cb = ao;
      gemm_bt<EPI_PV><<<dim3(1, 2, NB), 256, 0, stream>>>(p);
    }
    {  // proj + residual into x
      GP p{};
      p.A = ao; p.W = Wp; p.lda = 768; p.ldb = 768; p.ldc = 768;
      p.K = 768; p.Aclamp = MP; p.Wclamp = 768; p.Mv = MP; p.Nv = 768;
      p.bias = proj_b + layer * 768; p.Cf = x;
      gemm_bt<EPI_RES><<<dim3(6, 50, 1), 256, 0, stream>>>(p);
    }

    ln_kern<<<dim3(MP / 4), 256, 0, stream>>>(x, ln2_w + layer * 768, ln2_b + layer * 768, hb, MP);

    {  // FF1 + exact GELU -> bf16
      GP p{};
      p.A = hb; p.W = Wf1; p.lda = 768; p.ldb = 768; p.ldc = 3072;
      p.K = 768; p.Aclamp = MP; p.Wclamp = 3072; p.Mv = MP; p.Nv = 3072;
      p.bias = ff1_b + layer * 3072; p.Cb = gb;
      gemm_bt<EPI_GELU><<<dim3(24, 50, 1), 256, 0, stream>>>(p);
    }
    {  // FF2 + residual into x
      GP p{};
      p.A = gb; p.W = Wf2; p.lda = 3072; p.ldb = 3072; p.ldc = 768;
      p.K = 3072; p.Aclamp = MP; p.Wclamp = 768; p.Mv = MP; p.Nv = 768;
      p.bias = ff2_b + layer * 768; p.Cf = x;
      gemm_bt<EPI_RES><<<dim3(6, 50, 1), 256, 0, stream>>>(p);
    }
  }

  // head
  latent_kern<<<dim3((Bc * Dc + 255) / 256), 256, 0, stream>>>(x, lat);
  {  // head1 + tanh
    GP p{};
    p.A = lat; p.W = Wh1; p.lda = 768; p.ldb = 768; p.ldc = 3072;
    p.K = 768; p.Aclamp = Bc; p.Wclamp = 3072; p.Mv = Bc; p.Nv = 3072;
    p.bias = h1_b; p.Cb = tb;
    gemm_bt<EPI_TANH><<<dim3(24, 1, 1), 256, 0, stream>>>(p);
  }
  {  // head2 -> out fp32
    GP p{};
    p.A = tb; p.W = Wh2; p.lda = 3072; p.ldb = 3072; p.ldc = 1000;
    p.K = 3072; p.Aclamp = Bc; p.Wclamp = 1000; p.Mv = Bc; p.Nv = 1000;
    p.bias = h2_b; p.Cf = out;
    gemm_bt<EPI_F32><<<dim3(8, 1, 1), 256, 0, stream>>>(p);
  }
}

// Round 4
// 4571.761 us; speedup vs baseline: 1.0787x; 1.0787x over previous
//
#include <hip/hip_runtime.h>
#include <math.h>

typedef unsigned short u16;
using bf16x8 = __attribute__((ext_vector_type(8))) short;
using f32x4  = __attribute__((ext_vector_type(4))) float;

#define DEV __device__ __forceinline__

constexpr int Bc = 32, Cc = 3, IMGc = 224, Pc = 16, Dc = 768, Lc = 12, Hc = 12, NCLSc = 1000;
constexpr int NPc = 196, Nc = 197, DHc = 64;
constexpr int M0 = Bc * Nc;        // 6304 valid token rows
constexpr int MP = 6400;           // padded to 50*128
constexpr int MPATCH = Bc * NPc;   // 6272 = 49*128
constexpr int NKP = 224;           // padded key count (7*32)
constexpr int NB = Bc * Hc;        // 384 attention batches

DEV u16 f2b(float f) { union { float f; unsigned u; } c; c.f = f; unsigned r = c.u + 0x7fffu + ((c.u >> 16) & 1u); return (u16)(r >> 16); }
DEV float b2f(u16 b) { union { float f; unsigned u; } c; c.u = ((unsigned)b) << 16; return c.f; }

DEV float wsum(float v) {
#pragma unroll
  for (int m = 32; m >= 1; m >>= 1) v += __shfl_xor(v, m, 64);
  return v;
}
DEV float wmax(float v) {
#pragma unroll
  for (int m = 32; m >= 1; m >>= 1) v = fmaxf(v, __shfl_xor(v, m, 64));
  return v;
}

DEV void load_lds16(const u16* g, u16* l) {
  __builtin_amdgcn_global_load_lds((const __attribute__((address_space(1))) void*)g,
                                   (__attribute__((address_space(3))) void*)l, 16, 0, 0);
}

// ---------------- elementwise kernels ----------------

__global__ void cvt_kern(const float* __restrict__ in, u16* __restrict__ out, long n4) {
  long i = (long)blockIdx.x * 256 + threadIdx.x;
  if (i >= n4) return;
  float4 v = ((const float4*)in)[i];
  ushort4 r;
  r.x = f2b(v.x); r.y = f2b(v.y); r.z = f2b(v.z); r.w = f2b(v.w);
  ((ushort4*)out)[i] = r;
}

__global__ void patchify_kern(const float* __restrict__ img, u16* __restrict__ Xp) {
  int i = blockIdx.x * 256 + threadIdx.x;
  if (i >= MPATCH * Dc) return;
  int r = i / Dc, f = i - r * Dc;
  int b = r / NPc, g = r - b * NPc;
  int gi = g / 14, gj = g - gi * 14;
  int c = f % 3, t2 = f / 3;
  int pj = t2 & 15, pi = t2 >> 4;
  float v = img[(((long)(b * 3 + c) * 224) + gi * 16 + pi) * 224 + gj * 16 + pj];
  Xp[i] = f2b(v);
}

__global__ void addpos_kern(float* __restrict__ x, const float* __restrict__ cls, const float* __restrict__ pos) {
  int i = blockIdx.x * 256 + threadIdx.x;  // over M0*192 float4
  if (i >= M0 * 192) return;
  int row = i / 192, q = i - row * 192;
  int n = row % Nc;
  float4 p = ((const float4*)pos)[n * 192 + q];
  float4* dst = (float4*)x + (long)row * 192 + q;
  if (n == 0) {
    float4 cv = ((const float4*)cls)[q];
    float4 o; o.x = cv.x + p.x; o.y = cv.y + p.y; o.z = cv.z + p.z; o.w = cv.w + p.w;
    *dst = o;
  } else {
    float4 o = *dst;
    o.x += p.x; o.y += p.y; o.z += p.z; o.w += p.w;
    *dst = o;
  }
}

__global__ __launch_bounds__(256) void ln_kern(const float* __restrict__ x, const float* __restrict__ w,
                                               const float* __restrict__ b, u16* __restrict__ out, int rows) {
  int wid = threadIdx.x >> 6, l = threadIdx.x & 63;
  int row = blockIdx.x * 4 + wid;
  if (row >= rows) return;
  const float4* xr = (const float4*)(x + (long)row * Dc);
  float4 v[3];
#pragma unroll
  for (int i = 0; i < 3; ++i) v[i] = xr[i * 64 + l];
  float s = 0;
#pragma unroll
  for (int i = 0; i < 3; ++i) s += v[i].x + v[i].y + v[i].z + v[i].w;
  s = wsum(s);
  float mean = s * (1.0f / Dc);
  float ss = 0;
#pragma unroll
  for (int i = 0; i < 3; ++i) {
    float a0 = v[i].x - mean, a1 = v[i].y - mean, a2 = v[i].z - mean, a3 = v[i].w - mean;
    ss += a0 * a0 + a1 * a1 + a2 * a2 + a3 * a3;
  }
  ss = wsum(ss);
  float rs = rsqrtf(ss * (1.0f / Dc) + 1e-5f);
  const float4* w4 = (const float4*)w;
  const float4* b4 = (const float4*)b;
#pragma unroll
  for (int i = 0; i < 3; ++i) {
    int pos = i * 64 + l;
    float4 wv = w4[pos], bv = b4[pos];
    ushort4 o;
    o.x = f2b((v[i].x - mean) * rs * wv.x + bv.x);
    o.y = f2b((v[i].y - mean) * rs * wv.y + bv.y);
    o.z = f2b((v[i].z - mean) * rs * wv.z + bv.z);
    o.w = f2b((v[i].w - mean) * rs * wv.w + bv.w);
    ((ushort4*)out)[(long)row * 192 + pos] = o;
  }
}

// softmax in-place on bf16 scores S[z][224][224], valid rows/cols = 197
__global__ __launch_bounds__(256) void softmax_kern(u16* __restrict__ S) {
  int wid = threadIdx.x >> 6, l = threadIdx.x & 63;
  int q = blockIdx.x * 4 + wid;
  if (q >= Nc) return;
  int z = blockIdx.y;
  u16* rowp = S + ((long)z * NKP + q) * NKP;
  float vals[4];
  float mx = -1e30f;
#pragma unroll
  for (int i = 0; i < 4; ++i) {
    int col = i * 64 + l;
    float vv = (col < Nc) ? b2f(rowp[col]) : -1e30f;
    vals[i] = vv;
    mx = fmaxf(mx, vv);
  }
  mx = wmax(mx);
  float sum = 0;
#pragma unroll
  for (int i = 0; i < 4; ++i) {
    int col = i * 64 + l;
    float e = (col < Nc) ? expf(vals[i] - mx) : 0.f;
    vals[i] = e;
    sum += e;
  }
  sum = wsum(sum);
  float inv = 1.0f / sum;
#pragma unroll
  for (int i = 0; i < 4; ++i) {
    int col = i * 64 + l;
    if (col < NKP) rowp[col] = (col < Nc) ? f2b(vals[i] * inv) : (u16)0;
  }
}

__global__ void latent_kern(const float* __restrict__ x, u16* __restrict__ lat) {
  int i = blockIdx.x * 256 + threadIdx.x;
  if (i >= Bc * Dc) return;
  int b = i / Dc, d = i - b * Dc;
  lat[i] = f2b(x[(long)(b * Nc) * Dc + d]);
}

// ---------------- generic MFMA GEMM: C = A @ W^T (+epilogue) ----------------
// 2-phase double-buffered pipeline (T3-minimum), T2 both-sides LDS XOR
// swizzle (linear LDS dest for global_load_lds + pre-swizzled global source
// + swizzled ds_read), T1 bijective XCD swizzle (m204) for z==1 grids.

enum { EPI_F32 = 0, EPI_PATCH, EPI_BF16, EPI_PV, EPI_RES, EPI_GELU, EPI_TANH, EPI_QKV };

struct GP {
  const u16* A; const u16* W;
  int lda, ldb, ldc;
  long sA, sW, sC;          // per-batch strides (elements)
  int K;
  int Aclamp, Wclamp;       // valid source rows (staging clamp)
  int Mv, Nv;               // write guards
  int swz;                  // 1 = apply XCD swizzle (z==1 grids only)
  float alpha;
  const float* bias;
  float* Cf; u16* Cb;
  u16 *q, *k, *v;
};

template <int EPI>
__global__ __launch_bounds__(256) void gemm_bt(GP p) {
  __shared__ alignas(16) u16 As[2][128 * 32];
  __shared__ alignas(16) u16 Ws[2][128 * 32];
  const int z = blockIdx.z;
  const u16* Ab = p.A + (long)z * p.sA;
  const u16* Wb = p.W + (long)z * p.sW;
  const int tid = threadIdx.x;
  const int l = tid & 63, wid = tid >> 6;
  const int quad = l >> 4, lr = l & 15;
  const int wr = wid >> 1, wc = wid & 1;

  int tm, tn;
  if (p.swz) {
    const int gx = gridDim.x;
    const int nwg = gx * gridDim.y;
    const int orig = blockIdx.y * gx + blockIdx.x;
    const int q8 = nwg >> 3, r8 = nwg & 7;
    const int xcd = orig & 7, loc = orig >> 3;
    const int wgid = (xcd < r8 ? xcd * (q8 + 1) : r8 * (q8 + 1) + (xcd - r8) * q8) + loc;
    tm = (wgid / gx) * 128;
    tn = (wgid % gx) * 128;
  } else {
    tm = blockIdx.y * 128;
    tn = blockIdx.x * 128;
  }

  f32x4 acc[4][4];
  f32x4 z4 = {0.f, 0.f, 0.f, 0.f};
#pragma unroll
  for (int i = 0; i < 4; ++i)
#pragma unroll
    for (int j = 0; j < 4; ++j) acc[i][j] = z4;

  // staging geometry: thread -> LDS (row = tid>>2, 16B chunk = tid&3), linear dest.
  // T2: source column pre-swizzled so LDS(r,c) holds G(r, c ^ ((r>>1)&3)).
  const int sr = tid >> 2;
  const int s_sw = ((tid & 3) ^ ((sr >> 1) & 3)) * 8;
  const int ar0 = min(tm + sr, p.Aclamp - 1);
  const int ar1 = min(tm + 64 + sr, p.Aclamp - 1);
  const int wrr0 = min(tn + sr, p.Wclamp - 1);
  const int wrr1 = min(tn + 64 + sr, p.Wclamp - 1);
  const u16* a0 = Ab + (long)ar0 * p.lda + s_sw;
  const u16* a1 = Ab + (long)ar1 * p.lda + s_sw;
  const u16* w0 = Wb + (long)wrr0 * p.ldb + s_sw;
  const u16* w1 = Wb + (long)wrr1 * p.ldb + s_sw;

#define STAGE(buf, k0)                                  \
  do {                                                  \
    load_lds16(a0 + (k0), &As[buf][tid * 8]);           \
    load_lds16(a1 + (k0), &As[buf][2048 + tid * 8]);    \
    load_lds16(w0 + (k0), &Ws[buf][tid * 8]);           \
    load_lds16(w1 + (k0), &Ws[buf][2048 + tid * 8]);    \
  } while (0)

  const int nt = p.K >> 5;
  STAGE(0, 0);
  __syncthreads();
  int cur = 0;
  for (int t = 0; t < nt; ++t) {
    if (t + 1 < nt) STAGE(cur ^ 1, (t + 1) * 32);
    bf16x8 af[4], wf[4];
#pragma unroll
    for (int mi = 0; mi < 4; ++mi) {
      const int R = wr * 64 + mi * 16 + lr;
      const int qq = quad ^ ((R >> 1) & 3);
      af[mi] = *(const bf16x8*)((const char*)As[cur] + R * 64 + (qq << 4));
    }
#pragma unroll
    for (int ni = 0; ni < 4; ++ni) {
      const int R = wc * 64 + ni * 16 + lr;
      const int qq = quad ^ ((R >> 1) & 3);
      wf[ni] = *(const bf16x8*)((const char*)Ws[cur] + R * 64 + (qq << 4));
    }
#pragma unroll
    for (int mi = 0; mi < 4; ++mi)
#pragma unroll
      for (int ni = 0; ni < 4; ++ni)
        acc[mi][ni] = __builtin_amdgcn_mfma_f32_16x16x32_bf16(af[mi], wf[ni], acc[mi][ni], 0, 0, 0);
    __syncthreads();   // drains vmcnt(0): prefetched tile complete
    cur ^= 1;
  }
#undef STAGE

  if constexpr (EPI == EPI_QKV) {
    int hh[4], dh[4], ss[4]; float bv[4];
#pragma unroll
    for (int ni = 0; ni < 4; ++ni) {
      int col = tn + wc * 64 + ni * 16 + lr;
      hh[ni] = col / 192;
      int rem = col - hh[ni] * 192;
      dh[ni] = rem / 3;
      ss[ni] = rem - 3 * dh[ni];
      bv[ni] = p.bias[col];
    }
#pragma unroll
    for (int mi = 0; mi < 4; ++mi)
#pragma unroll
      for (int j = 0; j < 4; ++j) {
        int row = tm + wr * 64 + mi * 16 + quad * 4 + j;
        if (row >= p.Mv) continue;
        int b = row / Nc, n = row - Nc * b;
#pragma unroll
        for (int ni = 0; ni < 4; ++ni) {
          float val = acc[mi][ni][j] + bv[ni];
          if (ss[ni] == 0) {
            val *= p.alpha;
            p.q[(((long)(b * Hc + hh[ni])) * Nc + n) * DHc + dh[ni]] = f2b(val);
          } else if (ss[ni] == 1) {
            p.k[(((long)(b * Hc + hh[ni])) * Nc + n) * DHc + dh[ni]] = f2b(val);
          } else {
            p.v[(((long)(b * Hc + hh[ni])) * DHc + dh[ni]) * NKP + n] = f2b(val);
          }
        }
      }
  } else {
#pragma unroll
    for (int mi = 0; mi < 4; ++mi)
#pragma unroll
      for (int j = 0; j < 4; ++j) {
        int row = tm + wr * 64 + mi * 16 + quad * 4 + j;
        if (row >= p.Mv) continue;
#pragma unroll
        for (int ni = 0; ni < 4; ++ni) {
          int col = tn + wc * 64 + ni * 16 + lr;
          if (col >= p.Nv) continue;
          float val = acc[mi][ni][j];
          if constexpr (EPI == EPI_F32) {
            p.Cf[(long)z * p.sC + (long)row * p.ldc + col] = val + p.bias[col];
          }
          if constexpr (EPI == EPI_PATCH) {
            int b = row / NPc, t = row - NPc * b;
            p.Cf[((long)(b * Nc + 1 + t)) * p.ldc + col] = val + p.bias[col];
          }
          if constexpr (EPI == EPI_BF16) {
            p.Cb[(long)z * p.sC + (long)row * p.ldc + col] = f2b(val);
          }
          if constexpr (EPI == EPI_PV) {
            long off = (long)(z / Hc) * (Nc * Dc) + (long)(z % Hc) * DHc;
            p.Cb[off + (long)row * Dc + col] = f2b(val);
          }
          if constexpr (EPI == EPI_RES) {
            long ix = (long)row * p.ldc + col;
            p.Cf[ix] += val + p.bias[col];
          }
          if constexpr (EPI == EPI_GELU) {
            float t2 = val + p.bias[col];
            p.Cb[(long)row * p.ldc + col] = f2b(0.5f * t2 * (1.0f + erff(t2 * 0.70710678118f)));
          }
          if constexpr (EPI == EPI_TANH) {
            float t2 = val + p.bias[col];
            p.Cb[(long)row * p.ldc + col] = f2b(tanhf(t2));
          }
        }
      }
  }
}

// ---------------- host ----------------

static void cvt(const float* in, u16* out, long n, hipStream_t s) {
  long n4 = n / 4;
  cvt_kern<<<dim3((unsigned)((n4 + 255) / 256)), dim3(256), 0, s>>>(in, out, n4);
}

extern "C" void kernel_launch(void* const* d_in, const int* in_sizes, int n_in,
                              void* d_out, int out_size, void* d_ws, size_t ws_size,
                              hipStream_t stream) {
  const float* img     = (const float*)d_in[0];
  const float* patch_w = (const float*)d_in[1];
  const float* patch_b = (const float*)d_in[2];
  const float* cls_tok = (const float*)d_in[3];
  const float* pos_emb = (const float*)d_in[4];
  const float* ln1_w   = (const float*)d_in[5];
  const float* ln1_b   = (const float*)d_in[6];
  const float* qkv_w   = (const float*)d_in[7];
  const float* qkv_b   = (const float*)d_in[8];
  const float* proj_w  = (const float*)d_in[9];
  const float* proj_b  = (const float*)d_in[10];
  const float* ln2_w   = (const float*)d_in[11];
  const float* ln2_b   = (const float*)d_in[12];
  const float* ff1_w   = (const float*)d_in[13];
  const float* ff1_b   = (const float*)d_in[14];
  const float* ff2_w   = (const float*)d_in[15];
  const float* ff2_b   = (const float*)d_in[16];
  const float* h1_w    = (const float*)d_in[17];
  const float* h1_b    = (const float*)d_in[18];
  const float* h2_w    = (const float*)d_in[19];
  const float* h2_b    = (const float*)d_in[20];
  float* out = (float*)d_out;

  char* ws = (char*)d_ws;
  auto alloc = [&](long bytes) { char* p = ws; ws += (bytes + 255) & ~255L; return p; };
  u16* Wq  = (u16*)alloc(2304L * 768 * 2);
  u16* Wp  = (u16*)alloc(768L * 768 * 2);
  u16* Wf1 = (u16*)alloc(3072L * 768 * 2);
  u16* Wf2 = (u16*)alloc(768L * 3072 * 2);
  u16* Wpa = (u16*)alloc(768L * 768 * 2);
  u16* Wh1 = (u16*)alloc(3072L * 768 * 2);
  u16* Wh2 = (u16*)alloc(1000L * 3072 * 2);
  u16* Xp  = (u16*)alloc((long)MPATCH * Dc * 2);
  float* x = (float*)alloc((long)MP * Dc * 4);
  u16* hb  = (u16*)alloc((long)MP * Dc * 2);
  u16* qb  = (u16*)alloc((long)NB * Nc * DHc * 2);
  u16* kb  = (u16*)alloc((long)NB * Nc * DHc * 2);
  u16* vt  = (u16*)alloc((long)NB * DHc * NKP * 2);
  u16* S   = (u16*)alloc((long)NB * NKP * NKP * 2);
  u16* ao  = (u16*)alloc((long)MP * Dc * 2);
  u16* gb  = (u16*)alloc((long)MP * 3072 * 2);
  u16* lat = (u16*)alloc(Bc * 768L * 2);
  u16* tb  = (u16*)alloc(Bc * 3072L * 2);
  if ((size_t)(ws - (char*)d_ws) > ws_size) return;  // workspace too small

  // one-time weight converts
  cvt(patch_w, Wpa, 768L * 768, stream);
  cvt(h1_w, Wh1, 3072L * 768, stream);
  cvt(h2_w, Wh2, 1000L * 3072, stream);

  // patchify + patch GEMM + pos/cls
  patchify_kern<<<dim3((MPATCH * Dc + 255) / 256), dim3(256), 0, stream>>>(img, Xp);
  {
    GP p{};
    p.A = Xp; p.W = Wpa; p.lda = 768; p.ldb = 768; p.ldc = 768;
    p.K = 768; p.Aclamp = MPATCH; p.Wclamp = 768; p.Mv = MPATCH; p.Nv = 768;
    p.swz = 1; p.bias = patch_b; p.Cf = x;
    gemm_bt<EPI_PATCH><<<dim3(6, 49, 1), 256, 0, stream>>>(p);
  }
  addpos_kern<<<dim3((M0 * 192 + 255) / 256), dim3(256), 0, stream>>>(x, cls_tok, pos_emb);

  for (int layer = 0; layer < Lc; ++layer) {
    cvt(qkv_w + (long)layer * 2304 * 768, Wq, 2304L * 768, stream);
    cvt(proj_w + (long)layer * 768 * 768, Wp, 768L * 768, stream);
    cvt(ff1_w + (long)layer * 3072 * 768, Wf1, 3072L * 768, stream);
    cvt(ff2_w + (long)layer * 768 * 3072, Wf2, 768L * 3072, stream);

    ln_kern<<<dim3(MP / 4), 256, 0, stream>>>(x, ln1_w + layer * 768, ln1_b + layer * 768, hb, MP);

    {  // QKV + scatter (scale folded into q)
      GP p{};
      p.A = hb; p.W = Wq; p.lda = 768; p.ldb = 768;
      p.K = 768; p.Aclamp = MP; p.Wclamp = 2304; p.Mv = M0; p.Nv = 2304;
      p.swz = 1; p.alpha = 0.125f; p.bias = qkv_b + layer * 2304;
      p.q = qb; p.k = kb; p.v = vt;
      gemm_bt<EPI_QKV><<<dim3(18, 50, 1), 256, 0, stream>>>(p);
    }
    {  // scores: S[z] = Q[z] @ K[z]^T  (bf16 out)
      GP p{};
      p.A = qb; p.W = kb; p.lda = DHc; p.ldb = DHc; p.ldc = NKP;
      p.sA = (long)Nc * DHc; p.sW = (long)Nc * DHc; p.sC = (long)NKP * NKP;
      p.K = DHc; p.Aclamp = Nc; p.Wclamp = Nc; p.Mv = Nc; p.Nv = NKP;
      p.Cb = S;
      gemm_bt<EPI_BF16><<<dim3(2, 2, NB), 256, 0, stream>>>(p);
    }
    softmax_kern<<<dim3(50, NB), 256, 0, stream>>>(S);
    {  // PV: attnout[b, q, h*64+dh] = P[z] @ V[z]
      GP p{};
      p.A = S; p.W = vt; p.lda = NKP; p.ldb = NKP;
      p.sA = (long)NKP * NKP; p.sW = (long)DHc * NKP;
      p.K = NKP; p.Aclamp = Nc; p.Wclamp = DHc; p.Mv = Nc; p.Nv = DHc;
      p.Cb = ao;
      gemm_bt<EPI_PV><<<dim3(1, 2, NB), 256, 0, stream>>>(p);
    }
    {  // proj + residual into x
      GP p{};
      p.A = ao; p.W = Wp; p.lda = 768; p.ldb = 768; p.ldc = 768;
      p.K = 768; p.Aclamp = MP; p.Wclamp = 768; p.Mv = MP; p.Nv = 768;
      p.swz = 1; p.bias = proj_b + layer * 768; p.Cf = x;
      gemm_bt<EPI_RES><<<dim3(6, 50, 1), 256, 0, stream>>>(p);
    }

    ln_kern<<<dim3(MP / 4), 256, 0, stream>>>(x, ln2_w + layer * 768, ln2_b + layer * 768, hb, MP);

    {  // FF1 + exact GELU -> bf16
      GP p{};
      p.A = hb; p.W = Wf1; p.lda = 768; p.ldb = 768; p.ldc = 3072;
      p.K = 768; p.Aclamp = MP; p.Wclamp = 3072; p.Mv = MP; p.Nv = 3072;
      p.swz = 1; p.bias = ff1_b + layer * 3072; p.Cb = gb;
      gemm_bt<EPI_GELU><<<dim3(24, 50, 1), 256, 0, stream>>>(p);
    }
    {  // FF2 + residual into x
      GP p{};
      p.A = gb; p.W = Wf2; p.lda = 3072; p.ldb = 3072; p.ldc = 768;
      p.K = 3072; p.Aclamp = MP; p.Wclamp = 768; p.Mv = MP; p.Nv = 768;
      p.swz = 1; p.bias = ff2_b + layer * 768; p.Cf = x;
      gemm_bt<EPI_RES><<<dim3(6, 50, 1), 256, 0, stream>>>(p);
    }
  }

  // head
  latent_kern<<<dim3((Bc * Dc + 255) / 256), 256, 0, stream>>>(x, lat);
  {  // head1 + tanh
    GP p{};
    p.A = lat; p.W = Wh1; p.lda = 768; p.ldb = 768; p.ldc = 3072;
    p.K = 768; p.Aclamp = Bc; p.Wclamp = 3072; p.Mv = Bc; p.Nv = 3072;
    p.swz = 1; p.bias = h1_b; p.Cb = tb;
    gemm_bt<EPI_TANH><<<dim3(24, 1, 1), 256, 0, stream>>>(p);
  }
  {  // head2 -> out fp32
    GP p{};
    p.A = tb; p.W = Wh2; p.lda = 3072; p.ldb = 3072; p.ldc = 1000;
    p.K = 3072; p.Aclamp = Bc; p.Wclamp = 1000; p.Mv = Bc; p.Nv = 1000;
    p.swz = 1; p.bias = h2_b; p.Cf = out;
    gemm_bt<EPI_F32><<<dim3(8, 1, 1), 256, 0, stream>>>(p);
  }
}